// Round 4
// baseline (310.978 us; speedup 1.0000x reference)
//
#include <hip/hip_runtime.h>
#include <stdint.h>

// Problem constants
#define BB 2
#define SS 4096
#define EE 512
#define HH 8
#define DD 64
#define BH 16          // BB*HH
#define M_ROWS 8192    // BB*SS
#define N_COLS 1536    // 3*EE
#define K_DIM 512      // EE

typedef unsigned short u16;
typedef unsigned int u32;
typedef __attribute__((ext_vector_type(8))) __bf16 bf16x8;
typedef __attribute__((ext_vector_type(4))) float f32x4;
typedef __attribute__((ext_vector_type(16))) float f32x16;

__device__ __forceinline__ u16 f2bf(float f) {
  u32 u = __float_as_uint(f);
  u32 r = u + 0x7fffu + ((u >> 16) & 1u);   // RNE
  return (u16)(r >> 16);
}

__device__ __forceinline__ u32 cvtpk(float a, float b) {
  u32 r;
  asm("v_cvt_pk_bf16_f32 %0, %1, %2" : "=v"(r) : "v"(a), "v"(b));
  return r;
}

__device__ __forceinline__ float exp2f_fast(float x) {
#if __has_builtin(__builtin_amdgcn_exp2f)
  return __builtin_amdgcn_exp2f(x);
#else
  float r;
  asm("v_exp_f32 %0, %1" : "=v"(r) : "v"(x));
  return r;
#endif
}

// ---------------- fp32 -> bf16 convert (vectorized, grid-stride) ----------------
__global__ __launch_bounds__(256) void cvt_f32_bf16(const float* __restrict__ src,
                                                    u16* __restrict__ dst, int n) {
  int stride = gridDim.x * blockDim.x * 4;
  for (int i = (blockIdx.x * blockDim.x + threadIdx.x) * 4; i < n; i += stride) {
    float4 v = *(const float4*)(src + i);
    u32 lo = (u32)f2bf(v.x) | ((u32)f2bf(v.y) << 16);
    u32 hi = (u32)f2bf(v.z) | ((u32)f2bf(v.w) << 16);
    uint2 p; p.x = lo; p.y = hi;
    *(uint2*)(dst + i) = p;
  }
}

// ---------------- QKV GEMM: C[m][n] = sum_k X[m][k] * W[n][k] ----------------
// 128x128 tile, BK=64, 4 waves (each 64x64), 16x16x32 bf16 MFMA.
// Q scaled by 0.125*log2e (log2-domain softmax downstream). V stored TRANSPOSED
// [bh][d][s] via LDS-transposed coalesced epilogue.
#define BM 128
#define BN 128
#define BK 64

__global__ __launch_bounds__(256) void qkv_gemm(const u16* __restrict__ Xb,
                                                const u16* __restrict__ Wb,
                                                u16* __restrict__ Qg,
                                                u16* __restrict__ Kg,
                                                u16* __restrict__ Vt) {
  __shared__ u16 SH[BM * BK * 2];   // Al + Bl; reused as 128x128 C-tile for V epilogue
  u16* Al = SH;
  u16* Bl = SH + BM * BK;

  const int tid = threadIdx.x;
  const int lane = tid & 63;
  const int w = tid >> 6;
  const int wr = w >> 1, wc = w & 1;

  // XCD-aware swizzle of flat block id (768 = 8*96, bijective)
  const int flat = blockIdx.x;
  const int sw = (flat & 7) * 96 + (flat >> 3);
  const int bx = sw & 63, by = sw >> 6;
  const int m0 = bx * BM;
  const int n0 = by * BN;

  f32x4 acc[4][4] = {};
  uint4 ra[4], rb[4];

  auto loadT = [&](int kt) {
#pragma unroll
    for (int i = 0; i < 4; i++) {
      int c = i * 256 + tid;           // 16B chunks
      int row = c >> 3, seg = c & 7;
      ra[i] = *(const uint4*)(Xb + (size_t)(m0 + row) * K_DIM + kt * BK + seg * 8);
      rb[i] = *(const uint4*)(Wb + (size_t)(n0 + row) * K_DIM + kt * BK + seg * 8);
    }
  };
  auto storeT = [&]() {
#pragma unroll
    for (int i = 0; i < 4; i++) {
      int c = i * 256 + tid;
      int row = c >> 3, seg = c & 7;
      int byte = row * 128 + ((seg * 16) ^ ((row & 7) << 4));
      *(uint4*)((char*)Al + byte) = ra[i];
      *(uint4*)((char*)Bl + byte) = rb[i];
    }
  };

  loadT(0);
  const int NKT = K_DIM / BK;   // 8
  for (int kt = 0; kt < NKT; ++kt) {
    __syncthreads();
    storeT();
    __syncthreads();
    if (kt + 1 < NKT) loadT(kt + 1);

#pragma unroll
    for (int ks = 0; ks < 2; ++ks) {
      bf16x8 af[4], bfr[4];
#pragma unroll
      for (int t = 0; t < 4; t++) {
        int row = wr * 64 + t * 16 + (lane & 15);
        int byte = row * 128 + (((ks * 64) + (lane >> 4) * 16) ^ ((row & 7) << 4));
        af[t] = *(const bf16x8*)((const char*)Al + byte);
      }
#pragma unroll
      for (int t = 0; t < 4; t++) {
        int row = wc * 64 + t * 16 + (lane & 15);
        int byte = row * 128 + (((ks * 64) + (lane >> 4) * 16) ^ ((row & 7) << 4));
        bfr[t] = *(const bf16x8*)((const char*)Bl + byte);
      }
      __builtin_amdgcn_s_setprio(1);
#pragma unroll
      for (int am = 0; am < 4; am++)
#pragma unroll
        for (int bn = 0; bn < 4; bn++)
          acc[am][bn] = __builtin_amdgcn_mfma_f32_16x16x32_bf16(af[am], bfr[bn], acc[am][bn], 0, 0, 0);
      __builtin_amdgcn_s_setprio(0);
    }
  }

  // Epilogue. C layout: col = lane&15, row = (lane>>4)*4 + i  [m89-verified]
  const float qscale = 0.125f * 1.44269504f;   // 1/sqrt(64) * log2(e)
  if (by < 8) {
    // Q (by 0..3) and K (by 4..7): 32B-coalesced scatter
#pragma unroll
    for (int am = 0; am < 4; am++) {
      int mbase = m0 + wr * 64 + am * 16 + (lane >> 4) * 4;   // multiple of 4
#pragma unroll
      for (int bn = 0; bn < 4; bn++) {
        int n = n0 + wc * 64 + bn * 16 + (lane & 15);
        int which = n >> 9;            // 0=q 1=k
        int hh = (n >> 6) & 7, dd = n & 63;
        int b = mbase >> 12;
        int bh = b * HH + hh;
        u16* dst = (which == 0) ? Qg : Kg;
        float sc = (which == 0) ? qscale : 1.0f;
#pragma unroll
        for (int i = 0; i < 4; i++) {
          int s = (mbase + i) & 4095;
          dst[((size_t)bh * SS + s) * DD + dd] = f2bf(acc[am][bn][i] * sc);
        }
      }
    }
  } else {
    // V: transpose through LDS -> fully coalesced 16B stores to Vt[bh][d][s]
    __syncthreads();   // done with Al/Bl
#pragma unroll
    for (int am = 0; am < 4; am++) {
      int mloc = wr * 64 + am * 16 + (lane >> 4) * 4;
#pragma unroll
      for (int bn = 0; bn < 4; bn++) {
        int nl = wc * 64 + bn * 16 + (lane & 15);
        union { u16 h[4]; uint2 u; } pk;
#pragma unroll
        for (int i = 0; i < 4; i++) pk.h[i] = f2bf(acc[am][bn][i]);
        int byte = nl * 256 + ((mloc * 2) ^ ((nl & 7) << 4));
        *(uint2*)((char*)SH + byte) = pk.u;
      }
    }
    __syncthreads();
    const int b = m0 >> 12;
#pragma unroll
    for (int i = 0; i < 8; i++) {
      int c = i * 256 + tid;            // 2048 chunks of 16B
      int row = c >> 4, ch = c & 15;
      int byte = row * 256 + ((ch * 16) ^ ((row & 7) << 4));
      uint4 v = *(const uint4*)((const char*)SH + byte);
      int ng = n0 + row;                // all V
      int hh = (ng >> 6) & 7, dd = ng & 63;
      *(uint4*)(Vt + ((size_t)(b * HH + hh) * DD + dd) * SS + (m0 & 4095) + ch * 8) = v;
    }
  }
}

// ---------------- Flash attention, 2-way KV split ----------------
// grid: 1024 blocks (XCD-swizzled -> (qx, bh, z)); 4 warps x 32 q rows.
// S^T = mfma(K, Q) in log2 domain; in-reg P via cvt_pk + permlane32_swap;
// O^T = mfma(V^T, P^T). Partials (unnormalized O, m, l) to workspace.
#define KVB 64
#define NT (SS / KVB)     // 64
#define SPLIT 2
#define HT (NT / SPLIT)   // 32

__global__ __launch_bounds__(256) void flash_attn(const u16* __restrict__ Qg,
                                                  const u16* __restrict__ Kg,
                                                  const u16* __restrict__ Vt,
                                                  float* __restrict__ Opart,
                                                  float* __restrict__ Ml) {
  __shared__ __align__(16) char smem[32768];   // 2 bufs x (K 8KB + V^T 8KB)

  const int tid = threadIdx.x;
  const int lane = tid & 63;
  const int w = tid >> 6;
  const int hi = lane >> 5;          // 0/1
  const int lq = lane & 31;
  // XCD swizzle: 1024 = 8*128; per XCD: 4 (bh,z) groups x 32 q-tiles (KV L2-resident)
  const int flat = blockIdx.x;
  const int sw = ((flat & 7) << 7) | (flat >> 3);
  const int qx = sw & 31;
  const int bhz = sw >> 5;
  const int bh = bhz >> 1;
  const int z = bhz & 1;
  const int q0 = qx * 128 + w * 32;

  bf16x8 qf[4];
  {
    const u16* qp = Qg + ((size_t)bh * SS + q0 + lq) * DD + hi * 8;
#pragma unroll
    for (int ks = 0; ks < 4; ks++) qf[ks] = *(const bf16x8*)(qp + ks * 16);
  }

  f32x16 oa0 = {}, oa1 = {};
  float m = -1e30f, l = 0.f;

  uint4 rk[2], rv[2];
  auto loadKV = [&](int kt) {
#pragma unroll
    for (int i = 0; i < 2; i++) {
      int c = i * 256 + tid;
      int row = c >> 3, seg = c & 7;
      rk[i] = *(const uint4*)(Kg + ((size_t)bh * SS + kt * KVB + row) * DD + seg * 8);
      rv[i] = *(const uint4*)(Vt + ((size_t)bh * DD + row) * SS + kt * KVB + seg * 8);
    }
  };
  auto storeKV = [&](int buf) {
    char* kb = smem + buf * 16384;
    char* vb = kb + 8192;
#pragma unroll
    for (int i = 0; i < 2; i++) {
      int c = i * 256 + tid;
      int row = c >> 3, seg = c & 7;
      int byte = row * 128 + ((seg * 16) ^ ((row & 7) << 4));
      *(uint4*)(kb + byte) = rk[i];
      *(uint4*)(vb + byte) = rv[i];
    }
  };

  loadKV(z * HT);
  storeKV(0);
  __syncthreads();

  for (int t = 0; t < HT; ++t) {
    const int cur = t & 1;
    const char* Kc = smem + cur * 16384;
    const char* Vc = Kc + 8192;

    if (t + 1 < HT) loadKV(z * HT + t + 1);   // issue global loads early (T14)

    // ---- QK^T (swapped): S^T[key][q] in log2 units (scale folded into Q)
    f32x16 sa0 = {}, sa1 = {};
    __builtin_amdgcn_s_setprio(1);
#pragma unroll
    for (int ks = 0; ks < 4; ks++) {
      int col = ks * 32 + hi * 16;
      int r0 = lq, r1 = 32 + lq;
      bf16x8 kf0 = *(const bf16x8*)(Kc + r0 * 128 + (col ^ ((r0 & 7) << 4)));
      bf16x8 kf1 = *(const bf16x8*)(Kc + r1 * 128 + (col ^ ((r1 & 7) << 4)));
      sa0 = __builtin_amdgcn_mfma_f32_32x32x16_bf16(kf0, qf[ks], sa0, 0, 0, 0);
      sa1 = __builtin_amdgcn_mfma_f32_32x32x16_bf16(kf1, qf[ks], sa1, 0, 0, 0);
    }
    __builtin_amdgcn_s_setprio(0);

    // ---- online softmax (log2 domain; defer-max THR=8 -> P <= 256)
    float tm = -1e30f;
#pragma unroll
    for (int r = 0; r < 16; r++) tm = fmaxf(tm, fmaxf(sa0[r], sa1[r]));
    tm = fmaxf(tm, __shfl_xor(tm, 32));
    if (__any(tm > m + 8.f)) {
      float mnew = fmaxf(m, tm);
      float al = exp2f_fast(m - mnew);
      m = mnew;
      l *= al;
#pragma unroll
      for (int r = 0; r < 16; r++) { oa0[r] *= al; oa1[r] *= al; }
    }
    float rs = 0.f;
#pragma unroll
    for (int r = 0; r < 16; r++) {
      float p0 = exp2f_fast(sa0[r] - m);
      float p1 = exp2f_fast(sa1[r] - m);
      sa0[r] = p0; sa1[r] = p1;
      rs += p0 + p1;
    }
    rs += __shfl_xor(rs, 32);
    l += rs;

    // ---- P -> bf16 B-fragments (T12)
    bf16x8 paf[4];
#pragma unroll
    for (int kb = 0; kb < 2; kb++) {
#pragma unroll
      for (int h2 = 0; h2 < 2; h2++) {
        int base = h2 * 8;
        u32 a0, b0, a1, b1;
        if (kb == 0) {
          a0 = cvtpk(sa0[base + 0], sa0[base + 1]);
          b0 = cvtpk(sa0[base + 4], sa0[base + 5]);
          a1 = cvtpk(sa0[base + 2], sa0[base + 3]);
          b1 = cvtpk(sa0[base + 6], sa0[base + 7]);
        } else {
          a0 = cvtpk(sa1[base + 0], sa1[base + 1]);
          b0 = cvtpk(sa1[base + 4], sa1[base + 5]);
          a1 = cvtpk(sa1[base + 2], sa1[base + 3]);
          b1 = cvtpk(sa1[base + 6], sa1[base + 7]);
        }
        asm("v_permlane32_swap_b32 %0, %1" : "+v"(a0), "+v"(b0));
        asm("v_permlane32_swap_b32 %0, %1" : "+v"(a1), "+v"(b1));
        union { u32 d[4]; bf16x8 v; } u;
        u.d[0] = a0; u.d[1] = a1; u.d[2] = b0; u.d[3] = b1;
        paf[kb * 2 + h2] = u.v;
      }
    }

    // ---- PV (swapped): O^T += V^T x P^T
    __builtin_amdgcn_s_setprio(1);
#pragma unroll
    for (int ks = 0; ks < 4; ks++) {
      int col = ks * 32 + hi * 16;
      int r0 = lq, r1 = 32 + lq;
      bf16x8 vf0 = *(const bf16x8*)(Vc + r0 * 128 + (col ^ ((r0 & 7) << 4)));
      bf16x8 vf1 = *(const bf16x8*)(Vc + r1 * 128 + (col ^ ((r1 & 7) << 4)));
      oa0 = __builtin_amdgcn_mfma_f32_32x32x16_bf16(vf0, paf[ks], oa0, 0, 0, 0);
      oa1 = __builtin_amdgcn_mfma_f32_32x32x16_bf16(vf1, paf[ks], oa1, 0, 0, 0);
    }
    __builtin_amdgcn_s_setprio(0);

    if (t + 1 < HT) storeKV(cur ^ 1);
    __syncthreads();
  }

  // ---- partial epilogue: unnormalized O^T -> LDS -> coalesced f32x4 stores; m,l out
  if (hi == 0)
    *(float2*)(Ml + ((size_t)(z * BH + bh) * SS + q0 + lq) * 2) = make_float2(m, l);

  float* ow = (float*)(smem + w * 8192);   // [32 q][64 d] f32, swizzled
#pragma unroll
  for (int db = 0; db < 2; db++)
#pragma unroll
    for (int r = 0; r < 16; r++) {
      int d = db * 32 + (r & 3) + 8 * (r >> 2) + 4 * hi;
      float v = db ? oa1[r] : oa0[r];
      *(float*)((char*)ow + lq * 256 + ((d * 4) ^ ((lq & 7) << 4))) = v;
    }
  __syncthreads();
#pragma unroll
  for (int i = 0; i < 8; i++) {
    int c = i * 64 + lane;               // 512 chunks of 16B per warp
    int row = c >> 4, ch = c & 15;
    float4 v = *(const float4*)((const char*)ow + row * 256 + ((ch * 16) ^ ((row & 7) << 4)));
    *(float4*)(Opart + ((size_t)(z * BH + bh) * SS + q0 + row) * DD + ch * 4) = v;
  }
}

// ---------------- merge the 2 KV-split partials ----------------
__global__ __launch_bounds__(256) void merge_split(const float* __restrict__ Opart,
                                                   const float* __restrict__ Ml,
                                                   float* __restrict__ Out) {
  int idx = blockIdx.x * 256 + threadIdx.x;    // 1,048,576 = BH*SS*16
  int dq = idx & 15;
  int s = (idx >> 4) & (SS - 1);
  int bh = idx >> 16;
  float2 ml0 = *(const float2*)(Ml + ((size_t)bh * SS + s) * 2);
  float2 ml1 = *(const float2*)(Ml + ((size_t)(BH + bh) * SS + s) * 2);
  float M = fmaxf(ml0.x, ml1.x);
  float e0 = exp2f_fast(ml0.x - M);
  float e1 = exp2f_fast(ml1.x - M);
  float rden = 1.0f / (ml0.y * e0 + ml1.y * e1);
  e0 *= rden; e1 *= rden;
  float4 o0 = *(const float4*)(Opart + ((size_t)bh * SS + s) * DD + dq * 4);
  float4 o1 = *(const float4*)(Opart + ((size_t)(BH + bh) * SS + s) * DD + dq * 4);
  float4 o;
  o.x = o0.x * e0 + o1.x * e1;
  o.y = o0.y * e0 + o1.y * e1;
  o.z = o0.z * e0 + o1.z * e1;
  o.w = o0.w * e0 + o1.w * e1;
  int b = bh >> 3, hh = bh & 7;
  *(float4*)(Out + ((size_t)b * SS + s) * EE + hh * DD + dq * 4) = o;
}

// ---------------- launch ----------------
extern "C" void kernel_launch(void* const* d_in, const int* in_sizes, int n_in,
                              void* d_out, int out_size, void* d_ws, size_t ws_size,
                              hipStream_t stream) {
  const float* x = (const float*)d_in[0];
  const float* Wq = (const float*)d_in[1];

  u16* xb = (u16*)d_ws;                              // [8192][512] bf16   8.4MB
  u16* wb = xb + (size_t)M_ROWS * K_DIM;             // [1536][512]        1.5MB
  u16* Qg = wb + (size_t)N_COLS * K_DIM;             // [16][4096][64]     8.4MB (scaled, log2 domain)
  u16* Kg = Qg + (size_t)BH * SS * DD;               // [16][4096][64]     8.4MB
  u16* Vt = Kg + (size_t)BH * SS * DD;               // [16][64][4096]     8.4MB
  float* Opart = (float*)(Vt + (size_t)BH * SS * DD);// [2][16][4096][64] 33.5MB
  float* Ml = Opart + (size_t)SPLIT * BH * SS * DD;  // [2][16][4096][2]   1MB

  cvt_f32_bf16<<<2048, 256, 0, stream>>>(x, xb, M_ROWS * K_DIM);
  cvt_f32_bf16<<<768, 256, 0, stream>>>(Wq, wb, N_COLS * K_DIM);

  qkv_gemm<<<768, 256, 0, stream>>>(xb, wb, Qg, Kg, Vt);

  flash_attn<<<1024, 256, 0, stream>>>(Qg, Kg, Vt, Opart, Ml);

  merge_split<<<4096, 256, 0, stream>>>(Opart, Ml, (float*)d_out);
}

// Round 6
// 198.121 us; speedup vs baseline: 1.5696x; 1.5696x over previous
//
#include <hip/hip_runtime.h>
#include <stdint.h>

// Problem constants
#define BB 2
#define SS 4096
#define EE 512
#define HH 8
#define DD 64
#define BH 16          // BB*HH
#define M_ROWS 8192    // BB*SS
#define N_COLS 1536    // 3*EE
#define K_DIM 512      // EE

typedef unsigned short u16;
typedef unsigned int u32;
typedef __attribute__((ext_vector_type(8))) __bf16 bf16x8;
typedef __attribute__((ext_vector_type(4))) float f32x4;
typedef __attribute__((ext_vector_type(16))) float f32x16;

__device__ __forceinline__ u16 f2bf(float f) {
  u32 u = __float_as_uint(f);
  u32 r = u + 0x7fffu + ((u >> 16) & 1u);   // RNE
  return (u16)(r >> 16);
}

__device__ __forceinline__ u32 cvtpk(float a, float b) {
  u32 r;
  asm("v_cvt_pk_bf16_f32 %0, %1, %2" : "=v"(r) : "v"(a), "v"(b));
  return r;
}

__device__ __forceinline__ float exp2f_fast(float x) {
  float r;
  asm("v_exp_f32 %0, %1" : "=v"(r) : "v"(x));
  return r;
}

// global -> LDS direct DMA, 16B per lane. LDS dest = wave-uniform base + lane*16
// (linear); source address is per-lane (pre-swizzled by caller). CK-style casts:
// low 32 bits of a flat LDS address are the LDS byte offset.
__device__ __forceinline__ void gl_lds16(const void* g, void* l) {
  using gu32 = const __attribute__((address_space(1))) uint32_t;
  using lu32 = __attribute__((address_space(3))) uint32_t;
  __builtin_amdgcn_global_load_lds((gu32*)(uintptr_t)g,
                                   (lu32*)(uint32_t)(uintptr_t)l, 16, 0, 0);
}

// ---------------- fp32 -> bf16 convert (vectorized, grid-stride) ----------------
__global__ __launch_bounds__(256) void cvt_f32_bf16(const float* __restrict__ src,
                                                    u16* __restrict__ dst, int n) {
  int stride = gridDim.x * blockDim.x * 4;
  for (int i = (blockIdx.x * blockDim.x + threadIdx.x) * 4; i < n; i += stride) {
    float4 v = *(const float4*)(src + i);
    u32 lo = (u32)f2bf(v.x) | ((u32)f2bf(v.y) << 16);
    u32 hi = (u32)f2bf(v.z) | ((u32)f2bf(v.w) << 16);
    uint2 p; p.x = lo; p.y = hi;
    *(uint2*)(dst + i) = p;
  }
}

// ---------------- QKV GEMM: C[m][n] = sum_k X[m][k] * W[n][k] ----------------
// 128x128 tile, BK=64, 4 waves, 16x16x32 bf16 MFMA. Staging via global_load_lds
// (pre-swizzled source, linear LDS). Q scaled by 0.125*log2e; V stored transposed.
#define BM 128
#define BN 128
#define BK 64

__global__ __launch_bounds__(256, 3) void qkv_gemm(const u16* __restrict__ Xb,
                                                   const u16* __restrict__ Wb,
                                                   u16* __restrict__ Qg,
                                                   u16* __restrict__ Kg,
                                                   u16* __restrict__ Vt) {
  __shared__ __align__(16) u16 SH[BM * BK * 2];   // Al + Bl; reused for V epilogue
  u16* Al = SH;
  u16* Bl = SH + BM * BK;

  const int tid = threadIdx.x;
  const int lane = tid & 63;
  const int w = tid >> 6;
  const int wr = w >> 1, wc = w & 1;

  // XCD-aware swizzle of flat block id (768 = 8*96, bijective)
  const int flat = blockIdx.x;
  const int sw = (flat & 7) * 96 + (flat >> 3);
  const int bx = sw & 63, by = sw >> 6;
  const int m0 = bx * BM;
  const int n0 = by * BN;

  f32x4 acc[4][4] = {};

  // Stage one K-tile: A[128][64] and B[128][64] bf16, 16KB each.
  // LDS linear in 1KB wave-chunks; global source seg XOR'd by row&7 so that the
  // swizzled read (byte ^ ((row&7)<<4)) returns the natural layout.
  auto STAGE = [&](int kt) {
#pragma unroll
    for (int i = 0; i < 4; i++) {
      int chunk = w * 4 + i;                 // 0..15 (1KB each)
      int row = chunk * 8 + (lane >> 3);     // 0..127
      int seg = (lane & 7) ^ (row & 7);
      gl_lds16(Xb + (size_t)(m0 + row) * K_DIM + kt * BK + seg * 8, Al + chunk * 512);
      gl_lds16(Wb + (size_t)(n0 + row) * K_DIM + kt * BK + seg * 8, Bl + chunk * 512);
    }
  };

  const int NKT = K_DIM / BK;   // 8
  for (int kt = 0; kt < NKT; ++kt) {
    __syncthreads();            // previous tile's LDS reads done
    STAGE(kt);
    asm volatile("s_waitcnt vmcnt(0)" ::: "memory");
    __syncthreads();            // tile visible to all waves

#pragma unroll
    for (int ks = 0; ks < 2; ++ks) {
      bf16x8 af[4], bfr[4];
#pragma unroll
      for (int t = 0; t < 4; t++) {
        int row = wr * 64 + t * 16 + (lane & 15);
        int byte = row * 128 + (((ks * 64) + (lane >> 4) * 16) ^ ((row & 7) << 4));
        af[t] = *(const bf16x8*)((const char*)Al + byte);
      }
#pragma unroll
      for (int t = 0; t < 4; t++) {
        int row = wc * 64 + t * 16 + (lane & 15);
        int byte = row * 128 + (((ks * 64) + (lane >> 4) * 16) ^ ((row & 7) << 4));
        bfr[t] = *(const bf16x8*)((const char*)Bl + byte);
      }
      __builtin_amdgcn_s_setprio(1);
#pragma unroll
      for (int am = 0; am < 4; am++)
#pragma unroll
        for (int bn = 0; bn < 4; bn++)
          acc[am][bn] = __builtin_amdgcn_mfma_f32_16x16x32_bf16(af[am], bfr[bn], acc[am][bn], 0, 0, 0);
      __builtin_amdgcn_s_setprio(0);
    }
  }

  // Epilogue. C layout: col = lane&15, row = (lane>>4)*4 + i  [m89-verified]
  const float qscale = 0.125f * 1.44269504f;   // 1/sqrt(64) * log2(e)
  if (by < 8) {
    // Q (by 0..3) and K (by 4..7)
#pragma unroll
    for (int am = 0; am < 4; am++) {
      int mbase = m0 + wr * 64 + am * 16 + (lane >> 4) * 4;   // multiple of 4
#pragma unroll
      for (int bn = 0; bn < 4; bn++) {
        int n = n0 + wc * 64 + bn * 16 + (lane & 15);
        int which = n >> 9;            // 0=q 1=k
        int hh = (n >> 6) & 7, dd = n & 63;
        int b = mbase >> 12;
        int bh = b * HH + hh;
        u16* dst = (which == 0) ? Qg : Kg;
        float sc = (which == 0) ? qscale : 1.0f;
#pragma unroll
        for (int i = 0; i < 4; i++) {
          int s = (mbase + i) & 4095;
          dst[((size_t)bh * SS + s) * DD + dd] = f2bf(acc[am][bn][i] * sc);
        }
      }
    }
  } else {
    // V: transpose through LDS -> fully coalesced 16B stores to Vt[bh][d][s]
    __syncthreads();   // done with Al/Bl
#pragma unroll
    for (int am = 0; am < 4; am++) {
      int mloc = wr * 64 + am * 16 + (lane >> 4) * 4;
#pragma unroll
      for (int bn = 0; bn < 4; bn++) {
        int nl = wc * 64 + bn * 16 + (lane & 15);
        union { u16 h[4]; uint2 u; } pk;
#pragma unroll
        for (int i = 0; i < 4; i++) pk.h[i] = f2bf(acc[am][bn][i]);
        int byte = nl * 256 + ((mloc * 2) ^ ((nl & 7) << 4));
        *(uint2*)((char*)SH + byte) = pk.u;
      }
    }
    __syncthreads();
    const int b = m0 >> 12;
#pragma unroll
    for (int i = 0; i < 8; i++) {
      int c = i * 256 + tid;            // 2048 chunks of 16B
      int row = c >> 4, ch = c & 15;
      int byte = row * 256 + ((ch * 16) ^ ((row & 7) << 4));
      uint4 v = *(const uint4*)((const char*)SH + byte);
      int ng = n0 + row;                // all V
      int hh = (ng >> 6) & 7, dd = ng & 63;
      *(uint4*)(Vt + ((size_t)(b * HH + hh) * DD + dd) * SS + (m0 & 4095) + ch * 8) = v;
    }
  }
}

// ---------------- Flash attention, 2-way KV split, gload_lds staging ----------------
#define KVB 64
#define NT (SS / KVB)     // 64
#define SPLIT 2
#define HT (NT / SPLIT)   // 32

__global__ __launch_bounds__(256, 3) void flash_attn(const u16* __restrict__ Qg,
                                                     const u16* __restrict__ Kg,
                                                     const u16* __restrict__ Vt,
                                                     float* __restrict__ Opart,
                                                     float* __restrict__ Ml) {
  __shared__ __align__(16) char smem[32768];   // 2 bufs x (K 8KB + V^T 8KB)

  const int tid = threadIdx.x;
  const int lane = tid & 63;
  const int w = tid >> 6;
  const int hi = lane >> 5;          // 0/1
  const int lq = lane & 31;
  // XCD swizzle: 1024 = 8*128; per XCD: 4 (bh,z) groups x 32 q-tiles (KV L2-resident)
  const int flat = blockIdx.x;
  const int sw = ((flat & 7) << 7) | (flat >> 3);
  const int qx = sw & 31;
  const int bhz = sw >> 5;
  const int bh = bhz >> 1;
  const int z = bhz & 1;
  const int q0 = qx * 128 + w * 32;

  bf16x8 qf[4];
  {
    const u16* qp = Qg + ((size_t)bh * SS + q0 + lq) * DD + hi * 8;
#pragma unroll
    for (int ks = 0; ks < 4; ks++) qf[ks] = *(const bf16x8*)(qp + ks * 16);
  }

  f32x16 oa0 = {}, oa1 = {};
  float m = -1e30f, l = 0.f;

  // Stage K tile [64 keys][64 d] and V^T tile [64 d][64 keys] (8KB each) via
  // global_load_lds: LDS linear, source seg pre-swizzled (XOR row&7).
  auto STAGE = [&](int kt, int buf) {
    char* kb = smem + buf * 16384;
    char* vb = kb + 8192;
#pragma unroll
    for (int i = 0; i < 2; i++) {
      int chunk = w * 2 + i;                 // 0..7 (1KB each)
      int row = chunk * 8 + (lane >> 3);     // 0..63
      int seg = (lane & 7) ^ (row & 7);
      gl_lds16(Kg + ((size_t)bh * SS + (size_t)kt * KVB + row) * DD + seg * 8,
               kb + chunk * 1024);
      gl_lds16(Vt + ((size_t)bh * DD + row) * SS + (size_t)kt * KVB + seg * 8,
               vb + chunk * 1024);
    }
  };

  STAGE(z * HT, 0);
  asm volatile("s_waitcnt vmcnt(0)" ::: "memory");
  __syncthreads();

  for (int t = 0; t < HT; ++t) {
    const int cur = t & 1;
    const char* Kc = smem + cur * 16384;
    const char* Vc = Kc + 8192;

    if (t + 1 < HT) STAGE(z * HT + t + 1, cur ^ 1);   // DMA into other buffer

    // ---- QK^T (swapped): S^T[key][q] in log2 units (scale folded into Q)
    f32x16 sa0 = {}, sa1 = {};
    __builtin_amdgcn_s_setprio(1);
#pragma unroll
    for (int ks = 0; ks < 4; ks++) {
      int col = ks * 32 + hi * 16;
      int r0 = lq, r1 = 32 + lq;
      bf16x8 kf0 = *(const bf16x8*)(Kc + r0 * 128 + (col ^ ((r0 & 7) << 4)));
      bf16x8 kf1 = *(const bf16x8*)(Kc + r1 * 128 + (col ^ ((r1 & 7) << 4)));
      sa0 = __builtin_amdgcn_mfma_f32_32x32x16_bf16(kf0, qf[ks], sa0, 0, 0, 0);
      sa1 = __builtin_amdgcn_mfma_f32_32x32x16_bf16(kf1, qf[ks], sa1, 0, 0, 0);
    }
    __builtin_amdgcn_s_setprio(0);

    // ---- online softmax (log2 domain; defer-max THR=8; tree reductions)
    float t0 = -1e30f, t1 = -1e30f, t2 = -1e30f, t3 = -1e30f;
#pragma unroll
    for (int r = 0; r < 16; r += 4) {
      t0 = fmaxf(t0, fmaxf(sa0[r], sa1[r]));
      t1 = fmaxf(t1, fmaxf(sa0[r + 1], sa1[r + 1]));
      t2 = fmaxf(t2, fmaxf(sa0[r + 2], sa1[r + 2]));
      t3 = fmaxf(t3, fmaxf(sa0[r + 3], sa1[r + 3]));
    }
    float tm = fmaxf(fmaxf(t0, t1), fmaxf(t2, t3));
    tm = fmaxf(tm, __shfl_xor(tm, 32));
    if (__any(tm > m + 8.f)) {
      float mnew = fmaxf(m, tm);
      float al = exp2f_fast(m - mnew);
      m = mnew;
      l *= al;
#pragma unroll
      for (int r = 0; r < 16; r++) { oa0[r] *= al; oa1[r] *= al; }
    }
    float s0 = 0.f, s1 = 0.f, s2 = 0.f, s3 = 0.f;
#pragma unroll
    for (int r = 0; r < 16; r += 2) {
      float p00 = exp2f_fast(sa0[r] - m);
      float p01 = exp2f_fast(sa0[r + 1] - m);
      float p10 = exp2f_fast(sa1[r] - m);
      float p11 = exp2f_fast(sa1[r + 1] - m);
      sa0[r] = p00; sa0[r + 1] = p01; sa1[r] = p10; sa1[r + 1] = p11;
      s0 += p00; s1 += p01; s2 += p10; s3 += p11;
    }
    float rs = (s0 + s1) + (s2 + s3);
    rs += __shfl_xor(rs, 32);
    l += rs;

    // ---- P -> bf16 B-fragments (T12: cvt_pk + permlane32_swap)
    bf16x8 paf[4];
#pragma unroll
    for (int kb = 0; kb < 2; kb++) {
#pragma unroll
      for (int h2 = 0; h2 < 2; h2++) {
        int base = h2 * 8;
        u32 a0, b0, a1, b1;
        if (kb == 0) {
          a0 = cvtpk(sa0[base + 0], sa0[base + 1]);
          b0 = cvtpk(sa0[base + 4], sa0[base + 5]);
          a1 = cvtpk(sa0[base + 2], sa0[base + 3]);
          b1 = cvtpk(sa0[base + 6], sa0[base + 7]);
        } else {
          a0 = cvtpk(sa1[base + 0], sa1[base + 1]);
          b0 = cvtpk(sa1[base + 4], sa1[base + 5]);
          a1 = cvtpk(sa1[base + 2], sa1[base + 3]);
          b1 = cvtpk(sa1[base + 6], sa1[base + 7]);
        }
        asm("v_permlane32_swap_b32 %0, %1" : "+v"(a0), "+v"(b0));
        asm("v_permlane32_swap_b32 %0, %1" : "+v"(a1), "+v"(b1));
        union { u32 d[4]; bf16x8 v; } u;
        u.d[0] = a0; u.d[1] = a1; u.d[2] = b0; u.d[3] = b1;
        paf[kb * 2 + h2] = u.v;
      }
    }

    // ---- PV (swapped): O^T += V^T x P^T
    __builtin_amdgcn_s_setprio(1);
#pragma unroll
    for (int ks = 0; ks < 4; ks++) {
      int col = ks * 32 + hi * 16;
      int r0 = lq, r1 = 32 + lq;
      bf16x8 vf0 = *(const bf16x8*)(Vc + r0 * 128 + (col ^ ((r0 & 7) << 4)));
      bf16x8 vf1 = *(const bf16x8*)(Vc + r1 * 128 + (col ^ ((r1 & 7) << 4)));
      oa0 = __builtin_amdgcn_mfma_f32_32x32x16_bf16(vf0, paf[ks], oa0, 0, 0, 0);
      oa1 = __builtin_amdgcn_mfma_f32_32x32x16_bf16(vf1, paf[ks], oa1, 0, 0, 0);
    }
    __builtin_amdgcn_s_setprio(0);

    // next-tile DMA (issued before compute) must be complete before flip
    asm volatile("s_waitcnt vmcnt(0)" ::: "memory");
    __syncthreads();
  }

  // ---- partial epilogue: unnormalized O^T -> LDS -> coalesced f32x4 stores; m,l out
  if (hi == 0)
    *(float2*)(Ml + ((size_t)(z * BH + bh) * SS + q0 + lq) * 2) = make_float2(m, l);

  float* ow = (float*)(smem + w * 8192);   // [32 q][64 d] f32, swizzled
#pragma unroll
  for (int db = 0; db < 2; db++)
#pragma unroll
    for (int r = 0; r < 16; r++) {
      int d = db * 32 + (r & 3) + 8 * (r >> 2) + 4 * hi;
      float v = db ? oa1[r] : oa0[r];
      *(float*)((char*)ow + lq * 256 + ((d * 4) ^ ((lq & 7) << 4))) = v;
    }
  __syncthreads();
#pragma unroll
  for (int i = 0; i < 8; i++) {
    int c = i * 64 + lane;               // 512 chunks of 16B per warp
    int row = c >> 4, ch = c & 15;
    float4 v = *(const float4*)((const char*)ow + row * 256 + ((ch * 16) ^ ((row & 7) << 4)));
    *(float4*)(Opart + ((size_t)(z * BH + bh) * SS + q0 + row) * DD + ch * 4) = v;
  }
}

// ---------------- merge the 2 KV-split partials ----------------
__global__ __launch_bounds__(256) void merge_split(const float* __restrict__ Opart,
                                                   const float* __restrict__ Ml,
                                                   float* __restrict__ Out) {
  int idx = blockIdx.x * 256 + threadIdx.x;    // 1,048,576 = BH*SS*16
  int dq = idx & 15;
  int s = (idx >> 4) & (SS - 1);
  int bh = idx >> 16;
  float2 ml0 = *(const float2*)(Ml + ((size_t)bh * SS + s) * 2);
  float2 ml1 = *(const float2*)(Ml + ((size_t)(BH + bh) * SS + s) * 2);
  float M = fmaxf(ml0.x, ml1.x);
  float e0 = exp2f_fast(ml0.x - M);
  float e1 = exp2f_fast(ml1.x - M);
  float rden = 1.0f / (ml0.y * e0 + ml1.y * e1);
  e0 *= rden; e1 *= rden;
  float4 o0 = *(const float4*)(Opart + ((size_t)bh * SS + s) * DD + dq * 4);
  float4 o1 = *(const float4*)(Opart + ((size_t)(BH + bh) * SS + s) * DD + dq * 4);
  float4 o;
  o.x = o0.x * e0 + o1.x * e1;
  o.y = o0.y * e0 + o1.y * e1;
  o.z = o0.z * e0 + o1.z * e1;
  o.w = o0.w * e0 + o1.w * e1;
  int b = bh >> 3, hh = bh & 7;
  *(float4*)(Out + ((size_t)b * SS + s) * EE + hh * DD + dq * 4) = o;
}

// ---------------- launch ----------------
extern "C" void kernel_launch(void* const* d_in, const int* in_sizes, int n_in,
                              void* d_out, int out_size, void* d_ws, size_t ws_size,
                              hipStream_t stream) {
  const float* x = (const float*)d_in[0];
  const float* Wq = (const float*)d_in[1];

  u16* xb = (u16*)d_ws;                              // [8192][512] bf16   8.4MB
  u16* wb = xb + (size_t)M_ROWS * K_DIM;             // [1536][512]        1.5MB
  u16* Qg = wb + (size_t)N_COLS * K_DIM;             // [16][4096][64]     8.4MB (scaled, log2 domain)
  u16* Kg = Qg + (size_t)BH * SS * DD;               // [16][4096][64]     8.4MB
  u16* Vt = Kg + (size_t)BH * SS * DD;               // [16][64][4096]     8.4MB
  float* Opart = (float*)(Vt + (size_t)BH * SS * DD);// [2][16][4096][64] 33.5MB
  float* Ml = Opart + (size_t)SPLIT * BH * SS * DD;  // [2][16][4096][2]   1MB

  cvt_f32_bf16<<<2048, 256, 0, stream>>>(x, xb, M_ROWS * K_DIM);
  cvt_f32_bf16<<<768, 256, 0, stream>>>(Wq, wb, N_COLS * K_DIM);

  qkv_gemm<<<768, 256, 0, stream>>>(xb, wb, Qg, Kg, Vt);

  flash_attn<<<1024, 256, 0, stream>>>(Qg, Kg, Vt, Opart, Ml);

  merge_split<<<4096, 256, 0, stream>>>(Opart, Ml, (float*)d_out);
}

// Round 9
// 190.174 us; speedup vs baseline: 1.6352x; 1.0418x over previous
//
#include <hip/hip_runtime.h>
#include <stdint.h>

// Problem constants
#define BB 2
#define SS 4096
#define EE 512
#define HH 8
#define DD 64
#define BH 16          // BB*HH
#define M_ROWS 8192    // BB*SS
#define N_COLS 1536    // 3*EE
#define K_DIM 512      // EE

typedef unsigned short u16;
typedef unsigned int u32;
typedef __attribute__((ext_vector_type(8))) __bf16 bf16x8;
typedef __attribute__((ext_vector_type(4))) float f32x4;
typedef __attribute__((ext_vector_type(16))) float f32x16;

__device__ __forceinline__ u16 f2bf(float f) {
  u32 u = __float_as_uint(f);
  u32 r = u + 0x7fffu + ((u >> 16) & 1u);   // RNE
  return (u16)(r >> 16);
}

__device__ __forceinline__ u32 cvtpk(float a, float b) {
  u32 r;
  asm("v_cvt_pk_bf16_f32 %0, %1, %2" : "=v"(r) : "v"(a), "v"(b));
  return r;
}

__device__ __forceinline__ float exp2f_fast(float x) {
  float r;
  asm("v_exp_f32 %0, %1" : "=v"(r) : "v"(x));
  return r;
}

// global -> LDS direct DMA, 16B per lane. LDS dest = wave-uniform base + lane*16
// (linear); source address is per-lane (pre-swizzled by caller).
__device__ __forceinline__ void gl_lds16(const void* g, void* l) {
  using gu32 = const __attribute__((address_space(1))) uint32_t;
  using lu32 = __attribute__((address_space(3))) uint32_t;
  __builtin_amdgcn_global_load_lds((gu32*)(uintptr_t)g,
                                   (lu32*)(uint32_t)(uintptr_t)l, 16, 0, 0);
}

// ---------------- fp32 -> bf16 convert (vectorized, grid-stride) ----------------
__global__ __launch_bounds__(256) void cvt_f32_bf16(const float* __restrict__ src,
                                                    u16* __restrict__ dst, int n) {
  int stride = gridDim.x * blockDim.x * 4;
  for (int i = (blockIdx.x * blockDim.x + threadIdx.x) * 4; i < n; i += stride) {
    float4 v = *(const float4*)(src + i);
    u32 lo = (u32)f2bf(v.x) | ((u32)f2bf(v.y) << 16);
    u32 hi = (u32)f2bf(v.z) | ((u32)f2bf(v.w) << 16);
    uint2 p; p.x = lo; p.y = hi;
    *(uint2*)(dst + i) = p;
  }
}

// ---------------- QKV GEMM: C[m][n] = sum_k X[m][k] * W[n][k] ----------------
// 128x128 tile, BK=64, 4 waves, 16x16x32 bf16 MFMA. Staging via global_load_lds
// (pre-swizzled source, linear LDS). Q scaled by 0.125*log2e; V stored transposed.
#define BM 128
#define BN 128
#define BK 64

__global__ __launch_bounds__(256, 3) void qkv_gemm(const u16* __restrict__ Xb,
                                                   const u16* __restrict__ Wb,
                                                   u16* __restrict__ Qg,
                                                   u16* __restrict__ Kg,
                                                   u16* __restrict__ Vt) {
  __shared__ __align__(16) u16 SH[BM * BK * 2];   // Al + Bl; reused for V epilogue
  u16* Al = SH;
  u16* Bl = SH + BM * BK;

  const int tid = threadIdx.x;
  const int lane = tid & 63;
  const int w = tid >> 6;
  const int wr = w >> 1, wc = w & 1;

  // XCD-aware swizzle of flat block id (768 = 8*96, bijective)
  const int flat = blockIdx.x;
  const int sw = (flat & 7) * 96 + (flat >> 3);
  const int bx = sw & 63, by = sw >> 6;
  const int m0 = bx * BM;
  const int n0 = by * BN;

  f32x4 acc[4][4] = {};

  auto STAGE = [&](int kt) {
#pragma unroll
    for (int i = 0; i < 4; i++) {
      int chunk = w * 4 + i;                 // 0..15 (1KB each)
      int row = chunk * 8 + (lane >> 3);     // 0..127
      int seg = (lane & 7) ^ (row & 7);
      gl_lds16(Xb + (size_t)(m0 + row) * K_DIM + kt * BK + seg * 8, Al + chunk * 512);
      gl_lds16(Wb + (size_t)(n0 + row) * K_DIM + kt * BK + seg * 8, Bl + chunk * 512);
    }
  };

  const int NKT = K_DIM / BK;   // 8
  for (int kt = 0; kt < NKT; ++kt) {
    __syncthreads();            // previous tile's LDS reads done
    STAGE(kt);
    asm volatile("s_waitcnt vmcnt(0)" ::: "memory");
    __syncthreads();            // tile visible to all waves

#pragma unroll
    for (int ks = 0; ks < 2; ++ks) {
      bf16x8 af[4], bfr[4];
#pragma unroll
      for (int t = 0; t < 4; t++) {
        int row = wr * 64 + t * 16 + (lane & 15);
        int byte = row * 128 + (((ks * 64) + (lane >> 4) * 16) ^ ((row & 7) << 4));
        af[t] = *(const bf16x8*)((const char*)Al + byte);
      }
#pragma unroll
      for (int t = 0; t < 4; t++) {
        int row = wc * 64 + t * 16 + (lane & 15);
        int byte = row * 128 + (((ks * 64) + (lane >> 4) * 16) ^ ((row & 7) << 4));
        bfr[t] = *(const bf16x8*)((const char*)Bl + byte);
      }
      __builtin_amdgcn_s_setprio(1);
#pragma unroll
      for (int am = 0; am < 4; am++)
#pragma unroll
        for (int bn = 0; bn < 4; bn++)
          acc[am][bn] = __builtin_amdgcn_mfma_f32_16x16x32_bf16(af[am], bfr[bn], acc[am][bn], 0, 0, 0);
      __builtin_amdgcn_s_setprio(0);
    }
  }

  // Epilogue. C layout: col = lane&15, row = (lane>>4)*4 + i  [m89-verified]
  const float qscale = 0.125f * 1.44269504f;   // 1/sqrt(64) * log2(e)
  if (by < 8) {
    // Q (by 0..3) and K (by 4..7)
#pragma unroll
    for (int am = 0; am < 4; am++) {
      int mbase = m0 + wr * 64 + am * 16 + (lane >> 4) * 4;   // multiple of 4
#pragma unroll
      for (int bn = 0; bn < 4; bn++) {
        int n = n0 + wc * 64 + bn * 16 + (lane & 15);
        int which = n >> 9;            // 0=q 1=k
        int hh = (n >> 6) & 7, dd = n & 63;
        int b = mbase >> 12;
        int bh = b * HH + hh;
        u16* dst = (which == 0) ? Qg : Kg;
        float sc = (which == 0) ? qscale : 1.0f;
#pragma unroll
        for (int i = 0; i < 4; i++) {
          int s = (mbase + i) & 4095;
          dst[((size_t)bh * SS + s) * DD + dd] = f2bf(acc[am][bn][i] * sc);
        }
      }
    }
  } else {
    // V: transpose through LDS -> fully coalesced 16B stores to Vt[bh][d][s]
    __syncthreads();   // done with Al/Bl
#pragma unroll
    for (int am = 0; am < 4; am++) {
      int mloc = wr * 64 + am * 16 + (lane >> 4) * 4;
#pragma unroll
      for (int bn = 0; bn < 4; bn++) {
        int nl = wc * 64 + bn * 16 + (lane & 15);
        union { u16 h[4]; uint2 u; } pk;
#pragma unroll
        for (int i = 0; i < 4; i++) pk.h[i] = f2bf(acc[am][bn][i]);
        int byte = nl * 256 + ((mloc * 2) ^ ((nl & 7) << 4));
        *(uint2*)((char*)SH + byte) = pk.u;
      }
    }
    __syncthreads();
    const int b = m0 >> 12;
#pragma unroll
    for (int i = 0; i < 8; i++) {
      int c = i * 256 + tid;            // 2048 chunks of 16B
      int row = c >> 4, ch = c & 15;
      int byte = row * 256 + ((ch * 16) ^ ((row & 7) << 4));
      uint4 v = *(const uint4*)((const char*)SH + byte);
      int ng = n0 + row;                // all V
      int hh = (ng >> 6) & 7, dd = ng & 63;
      *(uint4*)(Vt + ((size_t)(b * HH + hh) * DD + dd) * SS + (m0 & 4095) + ch * 8) = v;
    }
  }
}

// ---------------- Flash attention, 2-way KV split, gload_lds staging ----------------
#define KVB 64
#define NT (SS / KVB)     // 64
#define SPLIT 2
#define HT (NT / SPLIT)   // 32

__global__ __launch_bounds__(256, 3) void flash_attn(const u16* __restrict__ Qg,
                                                     const u16* __restrict__ Kg,
                                                     const u16* __restrict__ Vt,
                                                     float* __restrict__ Opart,
                                                     float* __restrict__ Ml) {
  __shared__ __align__(16) char smem[32768];   // 2 bufs x (K 8KB + V^T 8KB)

  const int tid = threadIdx.x;
  const int lane = tid & 63;
  const int w = tid >> 6;
  const int hi = lane >> 5;          // 0/1
  const int lq = lane & 31;
  // XCD swizzle: 1024 = 8*128; per XCD: 4 (bh,z) groups x 32 q-tiles (KV L2-resident)
  const int flat = blockIdx.x;
  const int sw = ((flat & 7) << 7) | (flat >> 3);
  const int qx = sw & 31;
  const int bhz = sw >> 5;
  const int bh = bhz >> 1;
  const int z = bhz & 1;
  const int q0 = qx * 128 + w * 32;

  bf16x8 qf[4];
  {
    const u16* qp = Qg + ((size_t)bh * SS + q0 + lq) * DD + hi * 8;
#pragma unroll
    for (int ks = 0; ks < 4; ks++) qf[ks] = *(const bf16x8*)(qp + ks * 16);
  }

  // Hoisted, loop-invariant swizzled LDS byte offsets (K and V^T reads identical).
  int loff[8];
#pragma unroll
  for (int ks = 0; ks < 4; ks++) {
    int col = ks * 32 + hi * 16;
    loff[ks * 2 + 0] = lq * 128 + (col ^ ((lq & 7) << 4));
    loff[ks * 2 + 1] = (32 + lq) * 128 + (col ^ ((lq & 7) << 4));   // (32+lq)&7 == lq&7
  }

  f32x16 oa0 = {}, oa1 = {};
  float m = -1e30f, l = 0.f;

  auto STAGE = [&](int kt, int buf) {
    char* kb = smem + buf * 16384;
    char* vb = kb + 8192;
#pragma unroll
    for (int i = 0; i < 2; i++) {
      int chunk = w * 2 + i;                 // 0..7 (1KB each)
      int row = chunk * 8 + (lane >> 3);     // 0..63
      int seg = (lane & 7) ^ (row & 7);
      gl_lds16(Kg + ((size_t)bh * SS + (size_t)kt * KVB + row) * DD + seg * 8,
               kb + chunk * 1024);
      gl_lds16(Vt + ((size_t)bh * DD + row) * SS + (size_t)kt * KVB + seg * 8,
               vb + chunk * 1024);
    }
  };

  STAGE(z * HT, 0);
  asm volatile("s_waitcnt vmcnt(0)" ::: "memory");
  __syncthreads();

  for (int t = 0; t < HT; ++t) {
    const int cur = t & 1;
    const char* Kc = smem + cur * 16384;
    const char* Vc = Kc + 8192;

    if (t + 1 < HT) STAGE(z * HT + t + 1, cur ^ 1);   // DMA into other buffer

    // ---- QK^T (swapped): S^T[key][q] in log2 units (scale folded into Q)
    f32x16 sa0 = {}, sa1 = {};
    __builtin_amdgcn_s_setprio(1);
#pragma unroll
    for (int ks = 0; ks < 4; ks++) {
      bf16x8 kf0 = *(const bf16x8*)(Kc + loff[ks * 2 + 0]);
      bf16x8 kf1 = *(const bf16x8*)(Kc + loff[ks * 2 + 1]);
      sa0 = __builtin_amdgcn_mfma_f32_32x32x16_bf16(kf0, qf[ks], sa0, 0, 0, 0);
      sa1 = __builtin_amdgcn_mfma_f32_32x32x16_bf16(kf1, qf[ks], sa1, 0, 0, 0);
    }
    __builtin_amdgcn_s_setprio(0);

    // ---- online softmax (log2 domain; defer-max THR=8).
    // Max via nested fmaxf triples (v_max3 fusion; any-m is mathematically safe).
    float c0 = fmaxf(fmaxf(sa0[0], sa0[1]), sa0[2]);
    float c1 = fmaxf(fmaxf(sa0[8], sa0[9]), sa0[10]);
    float c2 = fmaxf(fmaxf(sa1[0], sa1[1]), sa1[2]);
    float c3 = fmaxf(fmaxf(sa1[8], sa1[9]), sa1[10]);
    c0 = fmaxf(fmaxf(c0, sa0[3]), sa0[4]);
    c1 = fmaxf(fmaxf(c1, sa0[11]), sa0[12]);
    c2 = fmaxf(fmaxf(c2, sa1[3]), sa1[4]);
    c3 = fmaxf(fmaxf(c3, sa1[11]), sa1[12]);
    c0 = fmaxf(fmaxf(c0, sa0[5]), sa0[6]);
    c1 = fmaxf(fmaxf(c1, sa0[13]), sa0[14]);
    c2 = fmaxf(fmaxf(c2, sa1[5]), sa1[6]);
    c3 = fmaxf(fmaxf(c3, sa1[13]), sa1[14]);
    c0 = fmaxf(fmaxf(c0, sa0[7]), c2);
    c1 = fmaxf(fmaxf(c1, sa0[15]), c3);
    c0 = fmaxf(fmaxf(c0, sa1[7]), sa1[15]);
    float tm = fmaxf(c0, c1);
    tm = fmaxf(tm, __shfl_xor(tm, 32));     // m must be consistent across halves
    if (__any(tm > m + 8.f)) {
      float mnew = fmaxf(m, tm);
      float al = exp2f_fast(m - mnew);
      m = mnew;
      l *= al;
      oa0 *= al;            // whole-vector: compiler may select v_pk_mul_f32
      oa1 *= al;
    }
    sa0 = sa0 - m;          // whole-vector: compiler may select v_pk_add_f32
    sa1 = sa1 - m;
#pragma unroll
    for (int r = 0; r < 16; r++) {
      sa0[r] = exp2f_fast(sa0[r]);
      sa1[r] = exp2f_fast(sa1[r]);
    }
    {
      f32x16 ps = sa0 + sa1;
      float rs = (((ps[0] + ps[1]) + (ps[2] + ps[3])) + ((ps[4] + ps[5]) + (ps[6] + ps[7])))
               + (((ps[8] + ps[9]) + (ps[10] + ps[11])) + ((ps[12] + ps[13]) + (ps[14] + ps[15])));
      l += rs;              // own-half only; cross-half sum deferred to epilogue (linear)
    }

    // ---- P -> bf16 B-fragments (T12: cvt_pk + permlane32_swap) — verified R2-R6
    bf16x8 paf[4];
#pragma unroll
    for (int kb = 0; kb < 2; kb++) {
#pragma unroll
      for (int h2 = 0; h2 < 2; h2++) {
        int base = h2 * 8;
        u32 a0, b0, a1, b1;
        if (kb == 0) {
          a0 = cvtpk(sa0[base + 0], sa0[base + 1]);
          b0 = cvtpk(sa0[base + 4], sa0[base + 5]);
          a1 = cvtpk(sa0[base + 2], sa0[base + 3]);
          b1 = cvtpk(sa0[base + 6], sa0[base + 7]);
        } else {
          a0 = cvtpk(sa1[base + 0], sa1[base + 1]);
          b0 = cvtpk(sa1[base + 4], sa1[base + 5]);
          a1 = cvtpk(sa1[base + 2], sa1[base + 3]);
          b1 = cvtpk(sa1[base + 6], sa1[base + 7]);
        }
        asm("v_permlane32_swap_b32 %0, %1" : "+v"(a0), "+v"(b0));
        asm("v_permlane32_swap_b32 %0, %1" : "+v"(a1), "+v"(b1));
        union { u32 d[4]; bf16x8 v; } u;
        u.d[0] = a0; u.d[1] = a1; u.d[2] = b0; u.d[3] = b1;
        paf[kb * 2 + h2] = u.v;
      }
    }

    // ---- PV (swapped): O^T += V^T x P^T
    __builtin_amdgcn_s_setprio(1);
#pragma unroll
    for (int ks = 0; ks < 4; ks++) {
      bf16x8 vf0 = *(const bf16x8*)(Vc + loff[ks * 2 + 0]);
      bf16x8 vf1 = *(const bf16x8*)(Vc + loff[ks * 2 + 1]);
      oa0 = __builtin_amdgcn_mfma_f32_32x32x16_bf16(vf0, paf[ks], oa0, 0, 0, 0);
      oa1 = __builtin_amdgcn_mfma_f32_32x32x16_bf16(vf1, paf[ks], oa1, 0, 0, 0);
    }
    __builtin_amdgcn_s_setprio(0);

    // next-tile DMA (issued before compute) must be complete before flip
    asm volatile("s_waitcnt vmcnt(0)" ::: "memory");
    __syncthreads();
  }

  // ---- epilogue: combine deferred cross-half l; store m,l; unnormalized O^T out
  l += __shfl_xor(l, 32);
  if (hi == 0)
    *(float2*)(Ml + ((size_t)(z * BH + bh) * SS + q0 + lq) * 2) = make_float2(m, l);

  float* ow = (float*)(smem + w * 8192);   // [32 q][64 d] f32, swizzled
#pragma unroll
  for (int db = 0; db < 2; db++)
#pragma unroll
    for (int r = 0; r < 16; r++) {
      int d = db * 32 + (r & 3) + 8 * (r >> 2) + 4 * hi;
      float v = db ? oa1[r] : oa0[r];
      *(float*)((char*)ow + lq * 256 + ((d * 4) ^ ((lq & 7) << 4))) = v;
    }
  __syncthreads();
#pragma unroll
  for (int i = 0; i < 8; i++) {
    int c = i * 64 + lane;               // 512 chunks of 16B per warp
    int row = c >> 4, ch = c & 15;
    float4 v = *(const float4*)((const char*)ow + row * 256 + ((ch * 16) ^ ((row & 7) << 4)));
    *(float4*)(Opart + ((size_t)(z * BH + bh) * SS + q0 + row) * DD + ch * 4) = v;
  }
}

// ---------------- merge the 2 KV-split partials ----------------
__global__ __launch_bounds__(256) void merge_split(const float* __restrict__ Opart,
                                                   const float* __restrict__ Ml,
                                                   float* __restrict__ Out) {
  int idx = blockIdx.x * 256 + threadIdx.x;    // 1,048,576 = BH*SS*16
  int dq = idx & 15;
  int s = (idx >> 4) & (SS - 1);
  int bh = idx >> 16;
  float2 ml0 = *(const float2*)(Ml + ((size_t)bh * SS + s) * 2);
  float2 ml1 = *(const float2*)(Ml + ((size_t)(BH + bh) * SS + s) * 2);
  float M = fmaxf(ml0.x, ml1.x);
  float e0 = exp2f_fast(ml0.x - M);
  float e1 = exp2f_fast(ml1.x - M);
  float rden = 1.0f / (ml0.y * e0 + ml1.y * e1);
  e0 *= rden; e1 *= rden;
  float4 o0 = *(const float4*)(Opart + ((size_t)bh * SS + s) * DD + dq * 4);
  float4 o1 = *(const float4*)(Opart + ((size_t)(BH + bh) * SS + s) * DD + dq * 4);
  float4 o;
  o.x = o0.x * e0 + o1.x * e1;
  o.y = o0.y * e0 + o1.y * e1;
  o.z = o0.z * e0 + o1.z * e1;
  o.w = o0.w * e0 + o1.w * e1;
  int b = bh >> 3, hh = bh & 7;
  *(float4*)(Out + ((size_t)b * SS + s) * EE + hh * DD + dq * 4) = o;
}

// ---------------- launch ----------------
extern "C" void kernel_launch(void* const* d_in, const int* in_sizes, int n_in,
                              void* d_out, int out_size, void* d_ws, size_t ws_size,
                              hipStream_t stream) {
  const float* x = (const float*)d_in[0];
  const float* Wq = (const float*)d_in[1];

  u16* xb = (u16*)d_ws;                              // [8192][512] bf16   8.4MB
  u16* wb = xb + (size_t)M_ROWS * K_DIM;             // [1536][512]        1.5MB
  u16* Qg = wb + (size_t)N_COLS * K_DIM;             // [16][4096][64]     8.4MB (scaled, log2 domain)
  u16* Kg = Qg + (size_t)BH * SS * DD;               // [16][4096][64]     8.4MB
  u16* Vt = Kg + (size_t)BH * SS * DD;               // [16][64][4096]     8.4MB
  float* Opart = (float*)(Vt + (size_t)BH * SS * DD);// [2][16][4096][64] 33.5MB
  float* Ml = Opart + (size_t)SPLIT * BH * SS * DD;  // [2][16][4096][2]   1MB

  cvt_f32_bf16<<<2048, 256, 0, stream>>>(x, xb, M_ROWS * K_DIM);
  cvt_f32_bf16<<<768, 256, 0, stream>>>(Wq, wb, N_COLS * K_DIM);

  qkv_gemm<<<768, 256, 0, stream>>>(xb, wb, Qg, Kg, Vt);

  flash_attn<<<1024, 256, 0, stream>>>(Qg, Kg, Vt, Opart, Ml);

  merge_split<<<4096, 256, 0, stream>>>(Opart, Ml, (float*)d_out);
}